// Round 5
// baseline (108.656 us; speedup 1.0000x reference)
//
#include <hip/hip_runtime.h>
#include <hip/hip_bf16.h>
#include <math.h>

// Problem dims (fixed by setup_inputs)
constexpr int B = 4, C = 256, H = 128, W = 128, N = 4096, A = 5;
constexpr int HWs = H * W;
constexpr float AROUND_R = 0.1f;
constexpr int NBANDS = 32;            // y-bands of 4 rows each
constexpr int NBINS  = B * NBANDS;    // 128
constexpr int NP     = B * N;         // 16384

__device__ __forceinline__ float bf2f(unsigned short u) {
    union { unsigned int i; float f; } x;
    x.i = ((unsigned int)u) << 16;
    return x.f;
}
__device__ __forceinline__ float wave_reduce_sum(float v) {
    #pragma unroll
    for (int off = 32; off > 0; off >>= 1)
        v += __shfl_xor(v, off);
    return v;
}

// ---- Transpose one image [B,C,HW] f32 -> interleaved [B,HW,2C] bf16 (img = 0/1).
// Two separate launches measured at HBM roofline (fused 1-launch variant regressed 2x).
__global__ __launch_bounds__(256) void transpose_conv(const float* __restrict__ in,
                                                      __hip_bfloat16* __restrict__ out,
                                                      int img) {
    constexpr int TILE = 32;
    __shared__ float t[TILE][C + 1];   // stride 257: conflict-free both phases
    const int tilesPerB = HWs / TILE;  // 512
    int bx = blockIdx.x;
    int b  = bx / tilesPerB;
    int hw0 = (bx % tilesPerB) * TILE;
    int tid  = threadIdx.x;
    int hw_l = tid & 31;
    int cg   = tid >> 5;  // 0..7

    const float* src = in + (size_t)b * C * HWs;
    #pragma unroll
    for (int ci = 0; ci < C / 8; ++ci) {
        int c = ci * 8 + cg;
        t[hw_l][c] = src[(size_t)c * HWs + hw0 + hw_l];  // coalesced along hw
    }
    __syncthreads();
    __hip_bfloat16* dst = out + ((size_t)b * HWs + hw0) * (2 * C) + img * C;
    #pragma unroll
    for (int hwi = 0; hwi < TILE; ++hwi) {
        dst[(size_t)hwi * 2 * C + tid] = __float2bfloat16(t[hwi][tid]);
    }
}

// ---- Spatial binning: bin = b*NBANDS + clamp(y_pix/4)  -------------------------
__global__ __launch_bounds__(256) void bin_hist(const float* __restrict__ pts,
                                                int* __restrict__ counts,
                                                int* __restrict__ bins) {
    int p = blockIdx.x * 256 + threadIdx.x;
    if (p >= NP) return;
    int b = p >> 12;
    float gy = pts[(size_t)p * 2 + 1];
    float y = (gy + 1.0f) * (H * 0.5f) - 0.5f;
    int band = min(max((int)floorf(y * 0.25f), 0), NBANDS - 1);
    int bin = b * NBANDS + band;
    bins[p] = bin;
    atomicAdd(&counts[bin], 1);
}

__global__ __launch_bounds__(64) void bin_scan(const int* __restrict__ counts,
                                               int* __restrict__ offsets) {
    int l = threadIdx.x;               // one wave, 2 bins/lane
    int a = counts[2 * l], b = counts[2 * l + 1];
    int s = a + b, inc = s;
    #pragma unroll
    for (int off = 1; off < 64; off <<= 1) {
        int t = __shfl_up(inc, off);
        if (l >= off) inc += t;
    }
    int ex = inc - s;                  // exclusive prefix
    offsets[2 * l]     = ex;
    offsets[2 * l + 1] = ex + a;
}

__global__ __launch_bounds__(256) void bin_scatter(const int* __restrict__ bins,
                                                   int* __restrict__ offsets,
                                                   int* __restrict__ sorted) {
    int p = blockIdx.x * 256 + threadIdx.x;
    if (p >= NP) return;
    int pos = atomicAdd(&offsets[bins[p]], 1);
    sorted[pos] = p;   // permutation only: output is order-independent
}

// ---- Main gather kernel: round-2 proven body (VGPR~40) + sorted order + XCD chunking.
__global__ __launch_bounds__(256) void soft_align_bf16(
    const __hip_bfloat16* __restrict__ imgs, // [B,HW,2C] bf16
    const float* __restrict__ pf,            // [B,N,C]
    const float* __restrict__ pts,           // [B,N,2]
    const float* __restrict__ ao,            // [B,A,N,2]
    const int*   __restrict__ sorted,        // [NP] spatially-sorted point ids
    float* __restrict__ out)                 // [B,N,C]
{
    int tid  = threadIdx.x;
    int lane = tid & 63;
    int wave = tid >> 6;
    // Inverse XCD swizzle: XCD k (bid%8==k) gets logical blocks [512k,512k+512) ->
    // a contiguous sorted-point range, walked in order (sliding L2 window).
    int lb = (blockIdx.x & 7) * 512 + (blockIdx.x >> 3);
    int pg = sorted[lb * 4 + wave];
    int b = pg >> 12, n = pg & (N - 1);
    size_t pn = (size_t)pg;

    const float* pf_p = pf + pn * C;
    float4 rep = *reinterpret_cast<const float4*>(pf_p + lane * 4);
    float na2 = rep.x * rep.x + rep.y * rep.y + rep.z * rep.z + rep.w * rep.w;
    na2 = wave_reduce_sum(na2);
    float na = fmaxf(sqrtf(na2), 1e-8f);

    float gx0 = pts[pn * 2 + 0];
    float gy0 = pts[pn * 2 + 1];

    float4 emb[A];
    float  sim[A];

    #pragma unroll
    for (int a = 0; a < A; ++a) {
        float aox = ao[(((size_t)b * A + a) * N + n) * 2 + 0];
        float aoy = ao[(((size_t)b * A + a) * N + n) * 2 + 1];
        float gx = fminf(fmaxf(gx0 + (aox * 2.0f - 0.5f) * (2.0f * AROUND_R), -1.0f), 1.0f);
        float gy = fminf(fmaxf(gy0 + (aoy * 2.0f - 0.5f) * (2.0f * AROUND_R), -1.0f), 1.0f);
        float x = (gx + 1.0f) * (W * 0.5f) - 0.5f;
        float y = (gy + 1.0f) * (H * 0.5f) - 0.5f;
        float fx0 = floorf(x), fy0 = floorf(y);
        float wx1 = x - fx0, wy1 = y - fy0;
        float wx0 = 1.0f - wx1, wy0 = 1.0f - wy1;
        int ix0 = (int)fx0, iy0 = (int)fy0;
        int ix1 = ix0 + 1, iy1 = iy0 + 1;
        bool vx0 = (ix0 >= 0) && (ix0 < W);
        bool vx1 = (ix1 >= 0) && (ix1 < W);
        bool vy0 = (iy0 >= 0) && (iy0 < H);
        bool vy1 = (iy1 >= 0) && (iy1 < H);
        int cx0 = min(max(ix0, 0), W - 1), cx1 = min(max(ix1, 0), W - 1);
        int cy0 = min(max(iy0, 0), H - 1), cy1 = min(max(iy1, 0), H - 1);

        int   idxs[4] = {cy0 * W + cx0, cy0 * W + cx1, cy1 * W + cx0, cy1 * W + cx1};
        float wgt[4]  = {wx0 * wy0, wx1 * wy0, wx0 * wy1, wx1 * wy1};
        bool  vld[4]  = {vx0 && vy0, vx1 && vy0, vx0 && vy1, vx1 && vy1};

        float4 feat = make_float4(0.f, 0.f, 0.f, 0.f);
        float4 em   = make_float4(0.f, 0.f, 0.f, 0.f);
        #pragma unroll
        for (int k = 0; k < 4; ++k) {
            if (vld[k]) {
                const ushort4* px = reinterpret_cast<const ushort4*>(
                    imgs + ((size_t)b * HWs + idxs[k]) * (2 * C));
                ushort4 xv = px[lane];       // x1 channels 4l..4l+3
                ushort4 ev = px[64 + lane];  // pe channels 4l..4l+3
                float wk = wgt[k];
                feat.x += wk * bf2f(xv.x); feat.y += wk * bf2f(xv.y);
                feat.z += wk * bf2f(xv.z); feat.w += wk * bf2f(xv.w);
                em.x   += wk * bf2f(ev.x); em.y   += wk * bf2f(ev.y);
                em.z   += wk * bf2f(ev.z); em.w   += wk * bf2f(ev.w);
            }
        }
        float dotv = rep.x * feat.x + rep.y * feat.y + rep.z * feat.z + rep.w * feat.w;
        float nb2  = feat.x * feat.x + feat.y * feat.y + feat.z * feat.z + feat.w * feat.w;
        dotv = wave_reduce_sum(dotv);
        nb2  = wave_reduce_sum(nb2);
        float nb = fmaxf(sqrtf(nb2), 1e-8f);
        sim[a] = dotv / (na * nb);
        emb[a] = em;
    }

    float m = sim[0];
    #pragma unroll
    for (int a = 1; a < A; ++a) m = fmaxf(m, sim[a]);
    float e[A], s = 0.f;
    #pragma unroll
    for (int a = 0; a < A; ++a) { e[a] = __expf(sim[a] - m); s += e[a]; }
    float inv = 1.0f / s;

    float4 acc = make_float4(0.f, 0.f, 0.f, 0.f);
    #pragma unroll
    for (int a = 0; a < A; ++a) {
        float wa = e[a] * inv;
        acc.x += wa * emb[a].x; acc.y += wa * emb[a].y;
        acc.z += wa * emb[a].z; acc.w += wa * emb[a].w;
    }
    float4 o = make_float4(rep.x + acc.x, rep.y + acc.y, rep.z + acc.z, rep.w + acc.w);
    *reinterpret_cast<float4*>(out + pn * C + lane * 4) = o;
}

extern "C" void kernel_launch(void* const* d_in, const int* in_sizes, int n_in,
                              void* d_out, int out_size, void* d_ws, size_t ws_size,
                              hipStream_t stream) {
    const float* x1  = (const float*)d_in[0];
    const float* pf  = (const float*)d_in[1];
    const float* pts = (const float*)d_in[2];
    const float* pe  = (const float*)d_in[3];
    const float* ao  = (const float*)d_in[4];
    float* out = (float*)d_out;

    // ws layout: imgs (64 MiB) | counts[128] | offsets[128] | bins[NP] | sorted[NP]
    __hip_bfloat16* imgs = (__hip_bfloat16*)d_ws;
    int* counts  = (int*)((char*)d_ws + (size_t)B * HWs * 2 * C * sizeof(__hip_bfloat16));
    int* offsets = counts + NBINS;
    int* bins    = offsets + NBINS;
    int* sorted  = bins + NP;

    hipMemsetAsync(counts, 0, NBINS * sizeof(int), stream);
    bin_hist   <<<NP / 256, 256, 0, stream>>>(pts, counts, bins);
    bin_scan   <<<1, 64, 0, stream>>>(counts, offsets);
    bin_scatter<<<NP / 256, 256, 0, stream>>>(bins, offsets, sorted);

    int tblocks = B * (HWs / 32);  // 2048
    transpose_conv<<<tblocks, 256, 0, stream>>>(x1, imgs, 0);
    transpose_conv<<<tblocks, 256, 0, stream>>>(pe, imgs, 1);

    soft_align_bf16<<<NP / 4, 256, 0, stream>>>(imgs, pf, pts, ao, sorted, out);
}

// Round 6
// 79.482 us; speedup vs baseline: 1.3671x; 1.3671x over previous
//
#include <hip/hip_runtime.h>
#include <hip/hip_bf16.h>
#include <math.h>

// Problem dims (fixed by setup_inputs)
constexpr int B = 4, C = 256, H = 128, W = 128, N = 4096, A = 5;
constexpr int HWs = H * W;
constexpr float AROUND_R = 0.1f;
constexpr int NP = B * N;  // 16384

__device__ __forceinline__ float ulo(unsigned u) {
    union { unsigned i; float f; } x; x.i = u << 16; return x.f;
}
__device__ __forceinline__ float uhi(unsigned u) {
    union { unsigned i; float f; } x; x.i = u & 0xffff0000u; return x.f;
}
// reduce within each 32-lane half (shfl_xor <=16 never crosses halves)
__device__ __forceinline__ float reduce32h(float v) {
    #pragma unroll
    for (int off = 16; off > 0; off >>= 1)
        v += __shfl_xor(v, off);
    return v;
}

// ---- Transpose one image [B,C,HW] f32 -> interleaved [B,HW,2C] bf16 (img = 0/1).
// Two separate launches measured at HBM roofline (fused 1-launch variant regressed 2x).
__global__ __launch_bounds__(256) void transpose_conv(const float* __restrict__ in,
                                                      __hip_bfloat16* __restrict__ out,
                                                      int img) {
    constexpr int TILE = 32;
    __shared__ float t[TILE][C + 1];   // stride 257: conflict-free both phases
    const int tilesPerB = HWs / TILE;  // 512
    int bx = blockIdx.x;
    int b  = bx / tilesPerB;
    int hw0 = (bx % tilesPerB) * TILE;
    int tid  = threadIdx.x;
    int hw_l = tid & 31;
    int cg   = tid >> 5;  // 0..7

    const float* src = in + (size_t)b * C * HWs;
    #pragma unroll
    for (int ci = 0; ci < C / 8; ++ci) {
        int c = ci * 8 + cg;
        t[hw_l][c] = src[(size_t)c * HWs + hw0 + hw_l];  // coalesced along hw
    }
    __syncthreads();
    __hip_bfloat16* dst = out + ((size_t)b * HWs + hw0) * (2 * C) + img * C;
    #pragma unroll
    for (int hwi = 0; hwi < TILE; ++hwi) {
        dst[(size_t)hwi * 2 * C + tid] = __float2bfloat16(t[hwi][tid]);
    }
}

// ---- Main gather kernel: half-wave split + 1-sample-lookahead pipeline + LDS spill.
// One wave per point. Lanes 0-31: x1 channels (8/lane); lanes 32-63: pe channels.
__global__ __launch_bounds__(256) void soft_align_v4(
    const ushort* __restrict__ imgs,  // [B,HW,2C] bf16
    const float* __restrict__ pf,     // [B,N,C]
    const float* __restrict__ pts,    // [B,N,2]
    const float* __restrict__ ao,     // [B,A,N,2]
    float* __restrict__ out)          // [B,N,C]
{
    __shared__ float spill[4][A][32][8];  // 20 KiB: per-wave, per-sample pe accumulators

    int tid = threadIdx.x, lane = tid & 63, wave = tid >> 6;
    int p = blockIdx.x * 4 + wave;
    int b = p >> 12, n = p & (N - 1);
    int cl = lane & 31;
    bool upper = lane >= 32;
    size_t pn = (size_t)p;

    // point center + all 5 around-offsets issued upfront (float2 each)
    float gx0 = pts[pn * 2 + 0];
    float gy0 = pts[pn * 2 + 1];
    float2 aov[A];
    #pragma unroll
    for (int a = 0; a < A; ++a)
        aov[a] = *reinterpret_cast<const float2*>(ao + (((size_t)b * A + a) * N + n) * 2);

    // rep: both halves load the same 8 channels
    const float* repp = pf + pn * C + cl * 8;
    float4 r0 = *reinterpret_cast<const float4*>(repp);
    float4 r1 = *reinterpret_cast<const float4*>(repp + 4);
    float rep[8] = {r0.x, r0.y, r0.z, r0.w, r1.x, r1.y, r1.z, r1.w};

    const ushort* ib = imgs + (size_t)b * HWs * (2 * C);

    // sample address/weight computation (branch-free; OOB -> weight 0, clamped idx)
    auto sample = [&](int a, int* idx, float* wgt) {
        float gx = fminf(fmaxf(gx0 + (aov[a].x * 2.0f - 0.5f) * (2.0f * AROUND_R), -1.0f), 1.0f);
        float gy = fminf(fmaxf(gy0 + (aov[a].y * 2.0f - 0.5f) * (2.0f * AROUND_R), -1.0f), 1.0f);
        float x = (gx + 1.0f) * (W * 0.5f) - 0.5f;
        float y = (gy + 1.0f) * (H * 0.5f) - 0.5f;
        float fx0 = floorf(x), fy0 = floorf(y);
        float wx1 = x - fx0, wy1 = y - fy0;
        float wx0 = 1.0f - wx1, wy0 = 1.0f - wy1;
        int ix0 = (int)fx0, iy0 = (int)fy0, ix1 = ix0 + 1, iy1 = iy0 + 1;
        bool vx0 = (ix0 >= 0) & (ix0 < W), vx1 = (ix1 >= 0) & (ix1 < W);
        bool vy0 = (iy0 >= 0) & (iy0 < H), vy1 = (iy1 >= 0) & (iy1 < H);
        int cx0 = min(max(ix0, 0), W - 1), cx1 = min(max(ix1, 0), W - 1);
        int cy0 = min(max(iy0, 0), H - 1), cy1 = min(max(iy1, 0), H - 1);
        idx[0] = cy0 * W + cx0; idx[1] = cy0 * W + cx1;
        idx[2] = cy1 * W + cx0; idx[3] = cy1 * W + cx1;
        wgt[0] = (vx0 && vy0) ? wx0 * wy0 : 0.0f;
        wgt[1] = (vx1 && vy0) ? wx1 * wy0 : 0.0f;
        wgt[2] = (vx0 && vy1) ? wx0 * wy1 : 0.0f;
        wgt[3] = (vx1 && vy1) ? wx1 * wy1 : 0.0f;
    };

    // double-buffered loads: one full sample (4 corners x 16B/lane) in flight
    uint4 vb[2][4];
    float wb[2][4];
    {
        int idx[4];
        sample(0, idx, wb[0]);
        #pragma unroll
        for (int k = 0; k < 4; ++k)
            vb[0][k] = reinterpret_cast<const uint4*>(ib + (size_t)idx[k] * (2 * C))[lane];
    }

    float dtp[A], nbp[A];
    float na2 = 0.f;
    #pragma unroll
    for (int j = 0; j < 8; ++j) na2 += rep[j] * rep[j];

    #pragma unroll
    for (int a = 0; a < A; ++a) {
        const int cur = a & 1, nxt = cur ^ 1;
        if (a < A - 1) {  // issue next sample's loads before consuming current
            int idx[4];
            sample(a + 1, idx, wb[nxt]);
            #pragma unroll
            for (int k = 0; k < 4; ++k)
                vb[nxt][k] = reinterpret_cast<const uint4*>(ib + (size_t)idx[k] * (2 * C))[lane];
        }
        float acc8[8];
        #pragma unroll
        for (int j = 0; j < 8; ++j) acc8[j] = 0.f;
        #pragma unroll
        for (int k = 0; k < 4; ++k) {
            float w = wb[cur][k];
            unsigned u0 = vb[cur][k].x, u1 = vb[cur][k].y, u2 = vb[cur][k].z, u3 = vb[cur][k].w;
            acc8[0] += w * ulo(u0); acc8[1] += w * uhi(u0);
            acc8[2] += w * ulo(u1); acc8[3] += w * uhi(u1);
            acc8[4] += w * ulo(u2); acc8[5] += w * uhi(u2);
            acc8[6] += w * ulo(u3); acc8[7] += w * uhi(u3);
        }
        float dt = 0.f, nb2 = 0.f;
        #pragma unroll
        for (int j = 0; j < 8; ++j) {
            dt  += rep[j] * acc8[j];
            nb2 += acc8[j] * acc8[j];
        }
        dtp[a] = dt; nbp[a] = nb2;
        if (upper) {  // persist pe accumulator in LDS, free the registers
            float* sp = &spill[wave][a][cl][0];
            *reinterpret_cast<float4*>(sp)     = make_float4(acc8[0], acc8[1], acc8[2], acc8[3]);
            *reinterpret_cast<float4*>(sp + 4) = make_float4(acc8[4], acc8[5], acc8[6], acc8[7]);
        }
    }

    // deferred reductions (11 independent chains -> pipelined shuffles)
    na2 = reduce32h(na2);
    float na = fmaxf(sqrtf(na2), 1e-8f);
    float sim[A];
    #pragma unroll
    for (int a = 0; a < A; ++a) {
        float dt  = reduce32h(dtp[a]);
        float nb2 = reduce32h(nbp[a]);
        float dt2  = __shfl_xor(dt, 32);   // lower half's (x1) values
        float nb22 = __shfl_xor(nb2, 32);
        dt  = upper ? dt2 : dt;
        nb2 = upper ? nb22 : nb2;
        sim[a] = dt / (na * fmaxf(sqrtf(nb2), 1e-8f));
    }

    // softmax over A (uniform across lanes)
    float m = sim[0];
    #pragma unroll
    for (int a = 1; a < A; ++a) m = fmaxf(m, sim[a]);
    float e[A], s = 0.f;
    #pragma unroll
    for (int a = 0; a < A; ++a) { e[a] = __expf(sim[a] - m); s += e[a]; }
    float inv = 1.0f / s;

    // upper half: weighted sum of spilled pe accumulators -> output
    if (upper) {
        float o[8];
        #pragma unroll
        for (int j = 0; j < 8; ++j) o[j] = rep[j];
        #pragma unroll
        for (int a = 0; a < A; ++a) {
            float wa = e[a] * inv;
            const float* sp = &spill[wave][a][cl][0];
            float4 s0 = *reinterpret_cast<const float4*>(sp);
            float4 s1 = *reinterpret_cast<const float4*>(sp + 4);
            o[0] += wa * s0.x; o[1] += wa * s0.y; o[2] += wa * s0.z; o[3] += wa * s0.w;
            o[4] += wa * s1.x; o[5] += wa * s1.y; o[6] += wa * s1.z; o[7] += wa * s1.w;
        }
        float* op = out + pn * C + cl * 8;
        *reinterpret_cast<float4*>(op)     = make_float4(o[0], o[1], o[2], o[3]);
        *reinterpret_cast<float4*>(op + 4) = make_float4(o[4], o[5], o[6], o[7]);
    }
}

extern "C" void kernel_launch(void* const* d_in, const int* in_sizes, int n_in,
                              void* d_out, int out_size, void* d_ws, size_t ws_size,
                              hipStream_t stream) {
    const float* x1  = (const float*)d_in[0];
    const float* pf  = (const float*)d_in[1];
    const float* pts = (const float*)d_in[2];
    const float* pe  = (const float*)d_in[3];
    const float* ao  = (const float*)d_in[4];
    float* out = (float*)d_out;

    __hip_bfloat16* imgs = (__hip_bfloat16*)d_ws;  // [B,HW,2C] bf16 = 64 MiB

    int tblocks = B * (HWs / 32);  // 2048
    transpose_conv<<<tblocks, 256, 0, stream>>>(x1, imgs, 0);
    transpose_conv<<<tblocks, 256, 0, stream>>>(pe, imgs, 1);
    soft_align_v4<<<NP / 4, 256, 0, stream>>>((const ushort*)imgs, pf, pts, ao, out);
}

// Round 7
// 66.122 us; speedup vs baseline: 1.6433x; 1.2021x over previous
//
#include <hip/hip_runtime.h>
#include <hip/hip_bf16.h>
#include <math.h>

// Problem dims (fixed by setup_inputs)
constexpr int B = 4, C = 256, H = 128, W = 128, N = 4096, A = 5;
constexpr int HWs = H * W;
constexpr float AROUND_R = 0.1f;
constexpr int NP = B * N;  // 16384

// ---------- bf16 helpers ----------
__device__ __forceinline__ float ulo(unsigned u) {
    union { unsigned i; float f; } x; x.i = u << 16; return x.f;
}
__device__ __forceinline__ float uhi(unsigned u) {
    union { unsigned i; float f; } x; x.i = u & 0xffff0000u; return x.f;
}
__device__ __forceinline__ float red64(float v) {
    #pragma unroll
    for (int off = 32; off > 0; off >>= 1)
        v += __shfl_xor(v, off);
    return v;
}

// ---------- fp8 e4m3fn helpers (HW path on gfx950, software fallback) ----------
#if __has_builtin(__builtin_amdgcn_cvt_pk_f32_fp8) && __has_builtin(__builtin_amdgcn_cvt_pk_fp8_f32)
#define FP8_HW 1
#endif

__device__ __forceinline__ unsigned enc_fp8_sw(float x) {
    unsigned s = (__float_as_uint(x) >> 31) << 7;
    float ax = fminf(fabsf(x), 448.0f);
    if (!(ax >= 0x1p-10f)) return s;              // underflow -> signed zero
    int e = (int)((__float_as_uint(ax) >> 23) & 0xff) - 127;
    e = e < -6 ? -6 : e;
    float q = rintf(ldexpf(ax, 3 - e));           // mantissa units
    int iq = (int)q;
    if (iq >= 16) { iq = 8; e += 1; }
    unsigned enc = (iq >= 8) ? (((unsigned)(e + 7) << 3) | (unsigned)(iq - 8))
                             : (unsigned)iq;       // subnormal (e == -6)
    return s | enc;
}
__device__ __forceinline__ float dec_fp8_sw(unsigned u) {
    unsigned s = u >> 7, E = (u >> 3) & 0xf, M = u & 7;
    float v = E ? __uint_as_float(((E + 120u) << 23) | (M << 20)) : (float)M * 0x1p-9f;
    return s ? -v : v;
}

__device__ __forceinline__ unsigned pack4_fp8(float a0, float a1, float a2, float a3) {
#ifdef FP8_HW
    int w = __builtin_amdgcn_cvt_pk_fp8_f32(a0, a1, 0, false);
    w = __builtin_amdgcn_cvt_pk_fp8_f32(a2, a3, w, true);
    return (unsigned)w;
#else
    return enc_fp8_sw(a0) | (enc_fp8_sw(a1) << 8) | (enc_fp8_sw(a2) << 16) | (enc_fp8_sw(a3) << 24);
#endif
}
__device__ __forceinline__ void fp8x4_to_f32(unsigned u, float* f) {
#ifdef FP8_HW
    auto lo = __builtin_amdgcn_cvt_pk_f32_fp8((int)u, false);
    auto hi = __builtin_amdgcn_cvt_pk_f32_fp8((int)u, true);
    f[0] = lo[0]; f[1] = lo[1]; f[2] = hi[0]; f[3] = hi[1];
#else
    f[0] = dec_fp8_sw(u & 0xff); f[1] = dec_fp8_sw((u >> 8) & 0xff);
    f[2] = dec_fp8_sw((u >> 16) & 0xff); f[3] = dec_fp8_sw(u >> 24);
#endif
}

// ---------- transpose x1: [B,C,HW] f32 -> [B,HW,C] fp8 (dword-packed writes) ----------
__global__ __launch_bounds__(256) void transpose_x1_fp8(const float* __restrict__ in,
                                                        unsigned* __restrict__ outw) {
    constexpr int TILE = 32;
    __shared__ float t[TILE][C + 1];
    const int tilesPerB = HWs / TILE;  // 512
    int bx = blockIdx.x;
    int b  = bx / tilesPerB;
    int hw0 = (bx % tilesPerB) * TILE;
    int tid  = threadIdx.x;
    int hw_l = tid & 31;
    int cg   = tid >> 5;

    const float* src = in + (size_t)b * C * HWs;
    #pragma unroll
    for (int ci = 0; ci < C / 8; ++ci) {
        int c = ci * 8 + cg;
        t[hw_l][c] = src[(size_t)c * HWs + hw0 + hw_l];
    }
    __syncthreads();
    unsigned* dst = outw + ((size_t)b * HWs + hw0) * (C / 4);
    int dq = tid & 63, pg = tid >> 6;
    #pragma unroll
    for (int it = 0; it < 8; ++it) {
        int pix = it * 4 + pg;
        float a0 = t[pix][dq * 4 + 0], a1 = t[pix][dq * 4 + 1];
        float a2 = t[pix][dq * 4 + 2], a3 = t[pix][dq * 4 + 3];
        dst[(size_t)pix * (C / 4) + dq] = pack4_fp8(a0, a1, a2, a3);
    }
}

// ---------- transpose pe: [B,C,HW] f32 -> [B,HW,C] bf16 (proven pattern) ----------
__global__ __launch_bounds__(256) void transpose_pe_bf16(const float* __restrict__ in,
                                                         __hip_bfloat16* __restrict__ out) {
    constexpr int TILE = 32;
    __shared__ float t[TILE][C + 1];
    const int tilesPerB = HWs / TILE;
    int bx = blockIdx.x;
    int b  = bx / tilesPerB;
    int hw0 = (bx % tilesPerB) * TILE;
    int tid  = threadIdx.x;
    int hw_l = tid & 31;
    int cg   = tid >> 5;

    const float* src = in + (size_t)b * C * HWs;
    #pragma unroll
    for (int ci = 0; ci < C / 8; ++ci) {
        int c = ci * 8 + cg;
        t[hw_l][c] = src[(size_t)c * HWs + hw0 + hw_l];
    }
    __syncthreads();
    __hip_bfloat16* dst = out + ((size_t)b * HWs + hw0) * C;
    #pragma unroll
    for (int hwi = 0; hwi < TILE; ++hwi) {
        dst[(size_t)hwi * C + tid] = __float2bfloat16(t[hwi][tid]);
    }
}

// ---------- main: one wave/point, 4 ch/lane, deferred emb, all 40 loads up front ----------
__global__ __launch_bounds__(256) void soft_align_v5(
    const unsigned char* __restrict__ x1f8,  // [B,HW,C] fp8
    const ushort* __restrict__ pebf,         // [B,HW,C] bf16
    const float* __restrict__ pf,            // [B,N,C]
    const float* __restrict__ pts,           // [B,N,2]
    const float* __restrict__ ao,            // [B,A,N,2]
    float* __restrict__ out)                 // [B,N,C]
{
    int tid = threadIdx.x, lane = tid & 63, wave = tid >> 6;
    int p = blockIdx.x * 4 + wave;
    int b = p >> 12, n = p & (N - 1);
    size_t pn = (size_t)p;

    float gx0 = pts[pn * 2 + 0];
    float gy0 = pts[pn * 2 + 1];
    float2 aov[A];
    #pragma unroll
    for (int a = 0; a < A; ++a)
        aov[a] = *reinterpret_cast<const float2*>(ao + (((size_t)b * A + a) * N + n) * 2);

    float4 rep4 = *reinterpret_cast<const float4*>(pf + pn * C + lane * 4);

    // --- sample math: wave-uniform corner indices (->SGPR) + masked weights ---
    int   sidx[A][4];
    float swgt[A][4];
    #pragma unroll
    for (int a = 0; a < A; ++a) {
        float gx = fminf(fmaxf(gx0 + (aov[a].x * 2.0f - 0.5f) * (2.0f * AROUND_R), -1.0f), 1.0f);
        float gy = fminf(fmaxf(gy0 + (aov[a].y * 2.0f - 0.5f) * (2.0f * AROUND_R), -1.0f), 1.0f);
        float x = (gx + 1.0f) * (W * 0.5f) - 0.5f;
        float y = (gy + 1.0f) * (H * 0.5f) - 0.5f;
        float fx0 = floorf(x), fy0 = floorf(y);
        float wx1 = x - fx0, wy1 = y - fy0;
        float wx0 = 1.0f - wx1, wy0 = 1.0f - wy1;
        int ix0 = (int)fx0, iy0 = (int)fy0, ix1 = ix0 + 1, iy1 = iy0 + 1;
        bool vx0 = (ix0 >= 0) & (ix0 < W), vx1 = (ix1 >= 0) & (ix1 < W);
        bool vy0 = (iy0 >= 0) & (iy0 < H), vy1 = (iy1 >= 0) & (iy1 < H);
        int cx0 = min(max(ix0, 0), W - 1), cx1 = min(max(ix1, 0), W - 1);
        int cy0 = min(max(iy0, 0), H - 1), cy1 = min(max(iy1, 0), H - 1);
        int id0 = cy0 * W + cx0, id1 = cy0 * W + cx1;
        int id2 = cy1 * W + cx0, id3 = cy1 * W + cx1;
        sidx[a][0] = __builtin_amdgcn_readfirstlane(id0);
        sidx[a][1] = __builtin_amdgcn_readfirstlane(id1);
        sidx[a][2] = __builtin_amdgcn_readfirstlane(id2);
        sidx[a][3] = __builtin_amdgcn_readfirstlane(id3);
        swgt[a][0] = (vx0 && vy0) ? wx0 * wy0 : 0.0f;
        swgt[a][1] = (vx1 && vy0) ? wx1 * wy0 : 0.0f;
        swgt[a][2] = (vx0 && vy1) ? wx0 * wy1 : 0.0f;
        swgt[a][3] = (vx1 && vy1) ? wx1 * wy1 : 0.0f;
    }

    // --- issue ALL x1 loads (20 x dword), then ALL pe loads (20 x uint2) ---
    const unsigned char* xb = x1f8 + (size_t)b * HWs * C;
    const ushort*        pb = pebf + (size_t)b * HWs * C;
    unsigned xv[A][4];
    #pragma unroll
    for (int a = 0; a < A; ++a)
        #pragma unroll
        for (int k = 0; k < 4; ++k)
            xv[a][k] = *reinterpret_cast<const unsigned*>(xb + (size_t)sidx[a][k] * C + lane * 4);
    uint2 pv[A][4];
    #pragma unroll
    for (int a = 0; a < A; ++a)
        #pragma unroll
        for (int k = 0; k < 4; ++k)
            pv[a][k] = *reinterpret_cast<const uint2*>(pb + (size_t)sidx[a][k] * C + lane * 4);

    // --- consume x1: per-sample feat -> dot/norm partials ---
    float na2 = rep4.x * rep4.x + rep4.y * rep4.y + rep4.z * rep4.z + rep4.w * rep4.w;
    float dt[A], nb[A];
    #pragma unroll
    for (int a = 0; a < A; ++a) {
        float f0 = 0.f, f1 = 0.f, f2 = 0.f, f3 = 0.f;
        #pragma unroll
        for (int k = 0; k < 4; ++k) {
            float w = swgt[a][k];
            float c4[4];
            fp8x4_to_f32(xv[a][k], c4);
            f0 += w * c4[0]; f1 += w * c4[1]; f2 += w * c4[2]; f3 += w * c4[3];
        }
        dt[a] = rep4.x * f0 + rep4.y * f1 + rep4.z * f2 + rep4.w * f3;
        nb[a] = f0 * f0 + f1 * f1 + f2 * f2 + f3 * f3;
    }

    // --- reductions (11 independent 6-step chains) ---
    na2 = red64(na2);
    #pragma unroll
    for (int a = 0; a < A; ++a) dt[a] = red64(dt[a]);
    #pragma unroll
    for (int a = 0; a < A; ++a) nb[a] = red64(nb[a]);
    float na = fmaxf(sqrtf(na2), 1e-8f);

    float sim[A];
    #pragma unroll
    for (int a = 0; a < A; ++a)
        sim[a] = dt[a] / (na * fmaxf(sqrtf(nb[a]), 1e-8f));

    // --- softmax over A (uniform across lanes) ---
    float m = sim[0];
    #pragma unroll
    for (int a = 1; a < A; ++a) m = fmaxf(m, sim[a]);
    float e[A], s = 0.f;
    #pragma unroll
    for (int a = 0; a < A; ++a) { e[a] = __expf(sim[a] - m); s += e[a]; }
    float inv = 1.0f / s;

    // --- deferred emb: out = rep + sum_{a,k} (w_a * wgt_ak) * pe ---
    float o0 = rep4.x, o1 = rep4.y, o2 = rep4.z, o3 = rep4.w;
    #pragma unroll
    for (int a = 0; a < A; ++a) {
        float wa = e[a] * inv;
        #pragma unroll
        for (int k = 0; k < 4; ++k) {
            float c = wa * swgt[a][k];
            unsigned u0 = pv[a][k].x, u1 = pv[a][k].y;
            o0 += c * ulo(u0); o1 += c * uhi(u0);
            o2 += c * ulo(u1); o3 += c * uhi(u1);
        }
    }
    *reinterpret_cast<float4*>(out + pn * C + lane * 4) = make_float4(o0, o1, o2, o3);
}

extern "C" void kernel_launch(void* const* d_in, const int* in_sizes, int n_in,
                              void* d_out, int out_size, void* d_ws, size_t ws_size,
                              hipStream_t stream) {
    const float* x1  = (const float*)d_in[0];
    const float* pf  = (const float*)d_in[1];
    const float* pts = (const float*)d_in[2];
    const float* pe  = (const float*)d_in[3];
    const float* ao  = (const float*)d_in[4];
    float* out = (float*)d_out;

    // ws: x1 fp8 [B,HW,C] = 16.78 MB | pe bf16 [B,HW,C] = 33.55 MB
    unsigned* x1f8w = (unsigned*)d_ws;
    __hip_bfloat16* pebf = (__hip_bfloat16*)((char*)d_ws + (size_t)B * HWs * C);

    int tblocks = B * (HWs / 32);  // 2048
    transpose_x1_fp8 <<<tblocks, 256, 0, stream>>>(x1, x1f8w);
    transpose_pe_bf16<<<tblocks, 256, 0, stream>>>(pe, pebf);
    soft_align_v5<<<NP / 4, 256, 0, stream>>>((const unsigned char*)x1f8w,
                                              (const ushort*)pebf, pf, pts, ao, out);
}